// Round 2
// baseline (860.831 us; speedup 1.0000x reference)
//
#include <hip/hip_runtime.h>
#include <stdint.h>
#include <string.h>

#define BB 256
#define TT 2048
#define DD 64

typedef _Float16 h2 __attribute__((ext_vector_type(2)));

__device__ __forceinline__ float rl0f(float v) {
    return __int_as_float(__builtin_amdgcn_readlane(__float_as_int(v), 0));
}

__global__ __launch_bounds__(64) void crf_fwd(
    const float* __restrict__ p,     // [B,T,D]
    const int*   __restrict__ y,     // [B,T,D] one-hot
    const int*   __restrict__ mask,  // [B,T]  1 = padding
    const float* __restrict__ tr,    // [D,D]
    float*       __restrict__ out)   // [B]
{
    __shared__ float ltr[DD * DD];
    const int b = blockIdx.x;
    const int lane = threadIdx.x & 63;

    const float L2E = 1.44269504f;
    const float LN2 = 0.69314718f;
    const float NEG5L2E = -7.21347520f;  // -(5)*log2(e)

    // --- setup: M2[dd] = {exp(T[2dd][lane]+5), exp(T[2dd+1][lane]+5)} as f16 pair
    //     (column `lane` of exp(T+5)); raw f32 T stashed in LDS for s2 lookups.
    h2 M2[32];
#pragma unroll
    for (int dd = 0; dd < 32; ++dd) {
        float t0 = tr[(2 * dd + 0) * DD + lane];
        float t1 = tr[(2 * dd + 1) * DD + lane];
        ltr[(2 * dd + 0) * DD + lane] = t0;
        ltr[(2 * dd + 1) * DD + lane] = t1;
        h2 m;
        m.x = (_Float16)__builtin_amdgcn_exp2f((t0 + 5.0f) * L2E);
        m.y = (_Float16)__builtin_amdgcn_exp2f((t1 + 5.0f) * L2E);
        M2[dd] = m;
    }
    __syncthreads();

    // --- valid length L = popcount(mask == 0)  (contiguous prefix)
    int L = 0;
    for (int k = 0; k < TT / 64; ++k) {
        int mk = mask[b * TT + k * 64 + lane];
        L += __popcll(__ballot(mk == 0));
    }

    const float* pb = p + (size_t)b * TT * DD;
    const int*   yb = y + (size_t)b * TT * DD;

    // --- t = 0 init
    float alpha = pb[lane];
    int y0 = yb[lane];
    float s1 = (y0 != 0) ? alpha : 0.0f;
    float s2 = 0.0f;
    int lp = (int)__builtin_ctzll(__ballot(y0 != 0));

    const int nsteps = L - 1;  // iterations t = 1 .. L-1  (L >= 1024)

    // one forward step: consumes p[t][lane] (pc) and y[t][lane] (yc)
    auto step = [&](float pc, int yc) {
        // --- emission + transition scores (uniform scalar path)
        unsigned long long bal = __ballot(yc != 0);
        int lc = (int)__builtin_ctzll(bal);
        s2 += ltr[lp * DD + lc];   // uniform-address LDS broadcast, all lanes add same value
        lp = lc;
        s1 += (yc != 0) ? pc : 0.0f;

        // --- alpha recurrence: u_d = exp(alpha_d - a0 - 5); S_e = sum_d u_d * exp(T[d][e]+5)
        float a0 = rl0f(alpha);
        float x = fmaf(alpha - a0, L2E, NEG5L2E);
        x = fminf(x, 15.9f);                       // f16-overflow safety net (never hit in practice)
        float uf = __builtin_amdgcn_exp2f(x);
        // neighbor's u via DPP quad_perm [1,0,3,2]; pack (u_2i, u_2i+1) into half2
        int un_i = __builtin_amdgcn_update_dpp(0, __float_as_int(uf), 0xB1, 0xF, 0xF, true);
        float un = __int_as_float(un_i);
        auto pk = __builtin_amdgcn_cvt_pkrtz(uf, un); // even lanes hold the valid (lo,hi) pair
        int upi;
        __builtin_memcpy(&upi, &pk, 4);

        float acc[4] = {0.f, 0.f, 0.f, 0.f};
#pragma unroll
        for (int dd = 0; dd < 32; ++dd) {
            int us = __builtin_amdgcn_readlane(upi, 2 * dd);
            h2 uu;
            __builtin_memcpy(&uu, &us, 4);
            acc[dd & 3] = __builtin_amdgcn_fdot2(uu, M2[dd], acc[dd & 3], false);
        }
        float S = (acc[0] + acc[1]) + (acc[2] + acc[3]);
        float lg = __builtin_amdgcn_logf(S);       // log2
        alpha = fmaf(LN2, lg, pc + a0);
    };

    // --- main loop, unrolled x8 with 8-deep p/y prefetch (covers ~900cyc HBM latency)
    const int U = 8;
    float pv[U];
    int   yv[U];
#pragma unroll
    for (int j = 0; j < U; ++j) {
        int t = 1 + j;  // nsteps >= 1023, always in range
        pv[j] = pb[t * DD + lane];
        yv[j] = yb[t * DD + lane];
    }
    int i = 0;
    for (; i + U <= nsteps; i += U) {
        float pn[U];
        int   yn[U];
#pragma unroll
        for (int j = 0; j < U; ++j) {
            int t = 1 + i + U + j;
            if (t > TT - 1) t = TT - 1;  // stay in-bounds; clamped values never consumed
            pn[j] = pb[t * DD + lane];
            yn[j] = yb[t * DD + lane];
        }
#pragma unroll
        for (int j = 0; j < U; ++j) step(pv[j], yv[j]);
#pragma unroll
        for (int j = 0; j < U; ++j) { pv[j] = pn[j]; yv[j] = yn[j]; }
    }
    for (; i < nsteps; ++i) {  // remainder (< 8 iters), fresh loads to avoid dynamic reg indexing
        int t = 1 + i;
        float pc = pb[t * DD + lane];
        int yc = yb[t * DD + lane];
        step(pc, yc);
    }

    // --- logZ = logsumexp(alpha at t = L-1); reduce s1 across lanes; s2 already uniform
    float m = alpha;
#pragma unroll
    for (int xm = 32; xm >= 1; xm >>= 1) m = fmaxf(m, __shfl_xor(m, xm, 64));
    float e = __builtin_amdgcn_exp2f((alpha - m) * L2E);
#pragma unroll
    for (int xm = 32; xm >= 1; xm >>= 1) e += __shfl_xor(e, xm, 64);
    float logZ = fmaf(LN2, __builtin_amdgcn_logf(e), m);
#pragma unroll
    for (int xm = 32; xm >= 1; xm >>= 1) s1 += __shfl_xor(s1, xm, 64);

    if (lane == 0) out[b] = logZ - s1 - s2;
}

extern "C" void kernel_launch(void* const* d_in, const int* in_sizes, int n_in,
                              void* d_out, int out_size, void* d_ws, size_t ws_size,
                              hipStream_t stream) {
    const float* p  = (const float*)d_in[0];
    const int*   y  = (const int*)d_in[1];
    const int*   mk = (const int*)d_in[2];
    const float* tr = (const float*)d_in[3];
    float* out = (float*)d_out;
    crf_fwd<<<dim3(BB), dim3(64), 0, stream>>>(p, y, mk, tr, out);
}